// Round 4
// baseline (10818.398 us; speedup 1.0000x reference)
//
#include <hip/hip_runtime.h>
#include <math.h>

#define H 1024
#define SEQ 256
#define VOUT 32000
typedef unsigned long long ull;
typedef unsigned int u32;

__device__ __forceinline__ float sigmoidf_(float x) { return 1.f / (1.f + expf(-x)); }

// ---------------------------------------------------------------------------
// Cross-XCD communication protocol (flag/data split, parity double-buffer):
//  * producers store payload words with relaxed agent-scope atomics (cache-
//    bypassing, coherent at the fabric, no cache-maintenance cost),
//  * __syncthreads() drains every wave's stores (compiler emits vmcnt(0)
//    before s_barrier), so payloads are globally visible,
//  * thread 0 posts ONE monotonic per-block flag word,
//  * consumers spin only on flags (16 lines/block/round, s_sleep backoff) —
//    NOT on the payload array (R2's mistake: 256-line poll storm saturated
//    the coherence point and inflated visibility latency),
//  * after detection: acquire fence (compiler ordering), one-shot payload
//    loads.
// Payload arrays are double-buffered by step parity so a fast producer can
// never overwrite a generation a slow consumer is still reading (needs a lap
// of 2, impossible: every step has full 256-block fan-in).
// ---------------------------------------------------------------------------
__device__ __forceinline__ u32 ldw(const u32* p) {
    return __hip_atomic_load(p, __ATOMIC_RELAXED, __HIP_MEMORY_SCOPE_AGENT);
}
__device__ __forceinline__ void stw(u32* p, u32 v) {
    __hip_atomic_store(p, v, __ATOMIC_RELAXED, __HIP_MEMORY_SCOPE_AGENT);
}
__device__ __forceinline__ void stf(u32* p, float v) { stw(p, __float_as_uint(v)); }
__device__ __forceinline__ float ldf(const u32* p) { return __uint_as_float(ldw(p)); }
__device__ __forceinline__ void pollw(const u32* p, u32 gen) {
    while (ldw(p) < gen) __builtin_amdgcn_s_sleep(1);
    __builtin_amdgcn_fence(__ATOMIC_ACQUIRE, "agent");
}
// gen-tagged u64 slot (single-value exchanges: scores)
__device__ __forceinline__ ull ldq(const ull* p) {
    return __hip_atomic_load(p, __ATOMIC_RELAXED, __HIP_MEMORY_SCOPE_AGENT);
}
__device__ __forceinline__ void stq(ull* p, u32 gen, float v) {
    ull x = ((ull)gen << 32) | (ull)__float_as_uint(v);
    __hip_atomic_store(p, x, __ATOMIC_RELAXED, __HIP_MEMORY_SCOPE_AGENT);
}
__device__ __forceinline__ float poll1(const ull* q, u32 tgt) {
    ull v;
    for (;;) {
        v = ldq(q);
        if ((u32)(v >> 32) >= tgt) break;
        __builtin_amdgcn_s_sleep(1);
    }
    return __uint_as_float((u32)v);
}

__device__ __forceinline__ float wsum(float v) {
#pragma unroll
    for (int m = 32; m > 0; m >>= 1) v += __shfl_xor(v, m);
    return v;
}
__device__ __forceinline__ float wmax(float v) {
#pragma unroll
    for (int m = 32; m > 0; m >>= 1) v = fmaxf(v, __shfl_xor(v, m));
    return v;
}

// ---------------------------------------------------------------------------
__global__ __launch_bounds__(256) void gather_kernel(
    const int* __restrict__ input_ids, const int* __restrict__ target_ids,
    const float* __restrict__ enc_emb, const float* __restrict__ dec_emb,
    float* __restrict__ enc_x, float* __restrict__ dec_e)
{
    int b = blockIdx.x, tid = threadIdx.x;
    if (b < SEQ) {
        int tok = input_ids[b];
        const float4* src = (const float4*)(enc_emb + (size_t)tok * H);
        float4* dst = (float4*)(enc_x + (size_t)b * H);
        dst[tid] = src[tid];
    } else {
        int t = b - SEQ;
        int tok = (t == 0) ? 1 : target_ids[t - 1];
        const float4* src = (const float4*)(dec_emb + (size_t)tok * H);
        float4* dst = (float4*)(dec_e + (size_t)t * H);
        dst[tid] = src[tid];
    }
}

// zero score slots (512 u32) + 3 flag arrays (768 u32) = 1280 u32 contiguous
__global__ __launch_bounds__(256) void init_kernel(u32* __restrict__ sync_base)
{
    int i = blockIdx.x * 256 + threadIdx.x;
    if (i < 1280) sync_base[i] = 0;
}

// ---------------------------------------------------------------------------
// Generic NT GEMM: C[m,n] = sum_k A[m*lda+offa+k] * B[n*ldb+k] (+ bias[n])
// ---------------------------------------------------------------------------
__global__ __launch_bounds__(256) void gemm_nt_kernel(
    const float* __restrict__ A, const float* __restrict__ B,
    const float* __restrict__ bias, float* __restrict__ C,
    int Kdim, int lda, int offa, int ldb, int ldc)
{
    __shared__ float As[16][68];
    __shared__ float Bs[16][68];
    const int tid = threadIdx.x;
    const int m0 = blockIdx.y * 64;
    const int n0 = blockIdx.x * 64;
    const int tr = (tid >> 4) << 2;
    const int tc = (tid & 15) << 2;
    const int lrow = tid >> 2;
    const int lk = (tid & 3) << 2;
    const float* Ab = A + (size_t)m0 * lda + offa;
    const float* Bb = B + (size_t)n0 * ldb;
    float acc[4][4] = {{0.f,0.f,0.f,0.f},{0.f,0.f,0.f,0.f},{0.f,0.f,0.f,0.f},{0.f,0.f,0.f,0.f}};

    for (int k0 = 0; k0 < Kdim; k0 += 16) {
        float4 av = *(const float4*)(Ab + (size_t)lrow * lda + (k0 + lk));
        float4 bv = *(const float4*)(Bb + (size_t)lrow * ldb + (k0 + lk));
        As[lk + 0][lrow] = av.x; As[lk + 1][lrow] = av.y;
        As[lk + 2][lrow] = av.z; As[lk + 3][lrow] = av.w;
        Bs[lk + 0][lrow] = bv.x; Bs[lk + 1][lrow] = bv.y;
        Bs[lk + 2][lrow] = bv.z; Bs[lk + 3][lrow] = bv.w;
        __syncthreads();
#pragma unroll
        for (int k = 0; k < 16; ++k) {
            float4 a = *(const float4*)(&As[k][tr]);
            float4 b = *(const float4*)(&Bs[k][tc]);
            acc[0][0] = fmaf(a.x, b.x, acc[0][0]);
            acc[0][1] = fmaf(a.x, b.y, acc[0][1]);
            acc[0][2] = fmaf(a.x, b.z, acc[0][2]);
            acc[0][3] = fmaf(a.x, b.w, acc[0][3]);
            acc[1][0] = fmaf(a.y, b.x, acc[1][0]);
            acc[1][1] = fmaf(a.y, b.y, acc[1][1]);
            acc[1][2] = fmaf(a.y, b.z, acc[1][2]);
            acc[1][3] = fmaf(a.y, b.w, acc[1][3]);
            acc[2][0] = fmaf(a.z, b.x, acc[2][0]);
            acc[2][1] = fmaf(a.z, b.y, acc[2][1]);
            acc[2][2] = fmaf(a.z, b.z, acc[2][2]);
            acc[2][3] = fmaf(a.z, b.w, acc[2][3]);
            acc[3][0] = fmaf(a.w, b.x, acc[3][0]);
            acc[3][1] = fmaf(a.w, b.y, acc[3][1]);
            acc[3][2] = fmaf(a.w, b.z, acc[3][2]);
            acc[3][3] = fmaf(a.w, b.w, acc[3][3]);
        }
        __syncthreads();
    }
#pragma unroll
    for (int i = 0; i < 4; ++i) {
#pragma unroll
        for (int j = 0; j < 4; ++j) {
            float v = acc[i][j];
            if (bias) v += bias[n0 + tc + j];
            C[(size_t)(m0 + tr + i) * ldc + (n0 + tc + j)] = v;
        }
    }
}

// ---------------------------------------------------------------------------
// Encoder: 256 blocks x 256 threads; wave w of block b owns unit u = b*4+w.
// Step t: consume h(t) [parity t&1, flag gen t; t=0 zeros from LDS],
// produce h(t+1) [parity (t+1)&1, flag gen t+1]. Final step also seeds the
// decoder's h arrays (gen 1, parity 0).
// ---------------------------------------------------------------------------
__global__ __launch_bounds__(256) void enc_rnn_kernel(
    const float* __restrict__ Wh, const float* __restrict__ bh,
    const float* __restrict__ gi_all,
    u32* __restrict__ h_data, u32* __restrict__ flag_h,
    u32* __restrict__ dec_h_data, u32* __restrict__ dec_flag_h,
    float* __restrict__ encH)
{
    __shared__ float h_s[H];
    const int tid = threadIdx.x, wave = tid >> 6, lane = tid & 63;
    const int b = blockIdx.x, u = b * 4 + wave;
    const float* wr = Wh + (size_t)u * H;
    const float* wz = Wh + (size_t)(u + H) * H;
    const float* wn = Wh + (size_t)(u + 2 * H) * H;
    const float bhr = bh[u], bhz = bh[H + u], bhn = bh[2 * H + u];

    for (int t = 0; t < SEQ; ++t) {
        float gir = gi_all[t * 3 * H + u];            // prefetch before wait
        float giz = gi_all[t * 3 * H + H + u];
        float gin = gi_all[t * 3 * H + 2 * H + u];
        if (t == 0) {
            ((float4*)h_s)[tid] = make_float4(0.f, 0.f, 0.f, 0.f);
        } else {
            pollw(flag_h + tid, (u32)t);
            const u32* src = h_data + ((t & 1) << 10) + tid * 4;
            float4 hv = make_float4(ldf(src), ldf(src + 1), ldf(src + 2), ldf(src + 3));
            ((float4*)h_s)[tid] = hv;
        }
        __syncthreads();

        float dr = 0.f, dz = 0.f, dn = 0.f;
#pragma unroll 4
        for (int k = lane; k < H; k += 64) {
            float x = h_s[k];
            dr = fmaf(wr[k], x, dr);
            dz = fmaf(wz[k], x, dz);
            dn = fmaf(wn[k], x, dn);
        }
        dr = wsum(dr); dz = wsum(dz); dn = wsum(dn);
        if (lane == 0) {
            float r = sigmoidf_(gir + dr + bhr);
            float z = sigmoidf_(giz + dz + bhz);
            float n = tanhf(gin + r * (dn + bhn));
            float h2 = (1.f - z) * n + z * h_s[u];
            stf(h_data + (((t + 1) & 1) << 10) + u, h2);
            if (t == SEQ - 1) stf(dec_h_data + u, h2);   // parity 0, dec gen 1
            encH[(size_t)t * H + u] = h2;
        }
        __syncthreads();                               // drain payload stores
        if (tid == 0) {
            stw(flag_h + b, (u32)(t + 1));
            if (t == SEQ - 1) stw(dec_flag_h + b, 1u);
        }
    }
}

// ---------------------------------------------------------------------------
// Decoder: 3 exchanges/step (h -> scores -> c -> h). Step t consumes h gen
// t+1 (parity t&1), posts score gen t+1 (u64 slots), c gen t+1 (parity t&1),
// h gen t+2 (parity (t+1)&1). Wh@h partial dots are computed inside the
// c-wait window (they need only h).
// ---------------------------------------------------------------------------
__global__ __launch_bounds__(256) void dec_rnn_kernel(
    const float* __restrict__ attn_W, const float* __restrict__ attn_e,
    const float* __restrict__ M, const float* __restrict__ comb_pre,
    const float* __restrict__ Wi, const float* __restrict__ Wh,
    const float* __restrict__ bi, const float* __restrict__ bh,
    u32* __restrict__ h_data, u32* __restrict__ flag_h,
    u32* __restrict__ c_data, u32* __restrict__ flag_c,
    ull* __restrict__ score_slots, float* __restrict__ hs_dec)
{
    __shared__ float h_s[H];
    __shared__ float c_s[H];
    __shared__ float a_s[SEQ];
    __shared__ float red8[8];
    const int tid = threadIdx.x, wave = tid >> 6, lane = tid & 63;
    const int b = blockIdx.x, u = b * 4 + wave;
    const float* arow = attn_W + (size_t)b * (2 * H) + H;
    const float* Mrow = M + (size_t)u * SEQ;
    const float* wir = Wi + (size_t)u * H;
    const float* wiz = Wi + (size_t)(u + H) * H;
    const float* win = Wi + (size_t)(u + 2 * H) * H;
    const float* whr = Wh + (size_t)u * H;
    const float* whz = Wh + (size_t)(u + H) * H;
    const float* whn = Wh + (size_t)(u + 2 * H) * H;
    const float bir = bi[u], biz = bi[H + u], bin = bi[2 * H + u];
    const float bhr = bh[u], bhz = bh[H + u], bhn = bh[2 * H + u];

    for (int t = 0; t < SEQ; ++t) {
        // ---- stage 1: h exchange + score[b] ----
        float ae = attn_e[t * SEQ + b];               // prefetch before wait
        float cpre = comb_pre[t * H + u];
        pollw(flag_h + tid, (u32)(t + 1));
        const u32* hsrc = h_data + ((t & 1) << 10) + tid * 4;
        float4 hv = make_float4(ldf(hsrc), ldf(hsrc + 1), ldf(hsrc + 2), ldf(hsrc + 3));
        ((float4*)h_s)[tid] = hv;
        __syncthreads();
        float p = 0.f;
#pragma unroll
        for (int k = tid; k < H; k += 256) p = fmaf(arow[k], h_s[k], p);
        p = wsum(p);
        if (lane == 0) red8[wave] = p;
        __syncthreads();
        if (tid == 0)
            stq(score_slots + b, (u32)(t + 1),
                red8[0] + red8[1] + red8[2] + red8[3] + ae);

        // ---- stage 2: softmax + c[u] ----
        float s = poll1(score_slots + tid, (u32)(t + 1));
        float m = wmax(s);
        if (lane == 0) red8[4 + wave] = m;            // disjoint from red8[0..3]
        __syncthreads();
        float mx = fmaxf(fmaxf(red8[4], red8[5]), fmaxf(red8[6], red8[7]));
        float ev = expf(s - mx);
        a_s[tid] = ev;
        float sm = wsum(ev);
        if (lane == 0) red8[wave] = sm;               // tid0 already consumed old
        __syncthreads();
        float inv = 1.f / (red8[0] + red8[1] + red8[2] + red8[3]);
        float pc = 0.f;
#pragma unroll
        for (int k = lane; k < SEQ; k += 64) pc = fmaf(a_s[k], Mrow[k], pc);
        pc = wsum(pc);
        if (lane == 0)
            stf(c_data + ((t & 1) << 10) + u, fmaxf(0.f, cpre + pc * inv));
        __syncthreads();                              // drain c stores
        if (tid == 0) stw(flag_c + b, (u32)(t + 1));

        // ---- overlapped with c-wait: Wh @ h partial dots ----
        float dhr = 0.f, dhz = 0.f, dhn = 0.f;
#pragma unroll 2
        for (int k = lane; k < H; k += 64) {
            float hvk = h_s[k];
            dhr = fmaf(whr[k], hvk, dhr);
            dhz = fmaf(whz[k], hvk, dhz);
            dhn = fmaf(whn[k], hvk, dhn);
        }

        // ---- stage 3: c exchange + GRU cell ----
        pollw(flag_c + tid, (u32)(t + 1));
        const u32* csrc = c_data + ((t & 1) << 10) + tid * 4;
        float4 cv = make_float4(ldf(csrc), ldf(csrc + 1), ldf(csrc + 2), ldf(csrc + 3));
        ((float4*)c_s)[tid] = cv;
        __syncthreads();
        float dir = 0.f, diz = 0.f, din = 0.f;
#pragma unroll 2
        for (int k = lane; k < H; k += 64) {
            float cvk = c_s[k];
            dir = fmaf(wir[k], cvk, dir);
            diz = fmaf(wiz[k], cvk, diz);
            din = fmaf(win[k], cvk, din);
        }
        dir = wsum(dir); diz = wsum(diz); din = wsum(din);
        dhr = wsum(dhr); dhz = wsum(dhz); dhn = wsum(dhn);
        if (lane == 0) {
            float r = sigmoidf_(dir + bir + dhr + bhr);
            float z = sigmoidf_(diz + biz + dhz + bhz);
            float n = tanhf(din + bin + r * (dhn + bhn));
            float h2 = (1.f - z) * n + z * h_s[u];
            stf(h_data + (((t + 1) & 1) << 10) + u, h2);
            hs_dec[(size_t)t * H + u] = h2;
        }
        __syncthreads();                              // drain h stores
        if (tid == 0) stw(flag_h + b, (u32)(t + 2));
    }
}

// ---------------------------------------------------------------------------
__global__ __launch_bounds__(256) void nll_kernel(
    const float* __restrict__ logits, const int* __restrict__ target_ids,
    float* __restrict__ nll)
{
    const int t = blockIdx.x, tid = threadIdx.x;
    __shared__ float red[256];
    const float* row = logits + (size_t)t * VOUT;
    float mx = -1e30f;
    for (int i = tid; i < VOUT; i += 256) mx = fmaxf(mx, row[i]);
    red[tid] = mx;
    __syncthreads();
    for (int off = 128; off > 0; off >>= 1) {
        if (tid < off) red[tid] = fmaxf(red[tid], red[tid + off]);
        __syncthreads();
    }
    mx = red[0];
    __syncthreads();
    float s = 0.f;
    for (int i = tid; i < VOUT; i += 256) s += expf(row[i] - mx);
    red[tid] = s;
    __syncthreads();
    for (int off = 128; off > 0; off >>= 1) {
        if (tid < off) red[tid] += red[tid + off];
        __syncthreads();
    }
    if (tid == 0) {
        float lse = mx + logf(red[0]);
        nll[t] = lse - row[target_ids[t]];
    }
}

__global__ __launch_bounds__(256) void sum_kernel(
    const float* __restrict__ nll, float* __restrict__ out)
{
    __shared__ float red[256];
    int tid = threadIdx.x;
    red[tid] = nll[tid];
    __syncthreads();
    for (int off = 128; off > 0; off >>= 1) {
        if (tid < off) red[tid] += red[tid + off];
        __syncthreads();
    }
    if (tid == 0) out[0] = red[0];
}

// ---------------------------------------------------------------------------
extern "C" void kernel_launch(void* const* d_in, const int* in_sizes, int n_in,
                              void* d_out, int out_size, void* d_ws, size_t ws_size,
                              hipStream_t stream)
{
    const int*   input_ids  = (const int*)d_in[0];
    const int*   target_ids = (const int*)d_in[1];
    const float* enc_emb = (const float*)d_in[2];
    const float* enc_Wi  = (const float*)d_in[3];
    const float* enc_Wh  = (const float*)d_in[4];
    const float* enc_bi  = (const float*)d_in[5];
    const float* enc_bh  = (const float*)d_in[6];
    const float* dec_emb = (const float*)d_in[7];
    const float* dec_Wi  = (const float*)d_in[8];
    const float* dec_Wh  = (const float*)d_in[9];
    const float* dec_bi  = (const float*)d_in[10];
    const float* dec_bh  = (const float*)d_in[11];
    const float* attn_W  = (const float*)d_in[12];
    const float* attn_b  = (const float*)d_in[13];
    const float* comb_W  = (const float*)d_in[14];
    const float* comb_b  = (const float*)d_in[15];
    const float* out_W   = (const float*)d_in[16];
    const float* out_b   = (const float*)d_in[17];
    float* out = (float*)d_out;

    // sync region first (8B aligned): score_slots(256 u64) | flags(3x256 u32)
    ull* score_slots = (ull*)d_ws;
    u32* sync_base   = (u32*)d_ws;                   // init zeroes 1280 u32
    u32* enc_flag_h  = (u32*)(score_slots + 256);
    u32* dec_flag_h  = enc_flag_h + 256;
    u32* dec_flag_c  = dec_flag_h + 256;
    // payload arrays (parity double-buffered)
    u32* enc_h_data  = dec_flag_c + 256;             // 2*1024
    u32* dec_h_data  = enc_h_data + 2048;            // 2*1024
    u32* dec_c_data  = dec_h_data + 2048;            // 2*1024
    float* ws = (float*)(dec_c_data + 2048);
    float* enc_x    = ws; ws += SEQ * H;
    float* dec_e    = ws; ws += SEQ * H;
    float* enc_gi   = ws; ws += SEQ * 3 * H;
    float* attn_e   = ws; ws += SEQ * SEQ;
    float* comb_pre = ws; ws += SEQ * H;
    float* Mmat     = ws; ws += H * SEQ;
    float* encH     = ws; ws += SEQ * H;
    float* hs_dec   = ws; ws += SEQ * H;
    float* nll      = ws; ws += SEQ;
    ws += (256 - ((ws - (float*)d_ws) & 255)) & 255;
    float* logits   = ws; ws += (size_t)SEQ * VOUT;

    // phase 0: gathers + zero sync words
    hipLaunchKernelGGL(gather_kernel, dim3(512), dim3(256), 0, stream,
                       input_ids, target_ids, enc_emb, dec_emb, enc_x, dec_e);
    hipLaunchKernelGGL(init_kernel, dim3(5), dim3(256), 0, stream, sync_base);

    // phase 1: batched pre-GEMMs
    hipLaunchKernelGGL(gemm_nt_kernel, dim3(3 * H / 64, SEQ / 64), dim3(256), 0, stream,
                       enc_x, enc_Wi, enc_bi, enc_gi, H, H, 0, H, 3 * H);
    hipLaunchKernelGGL(gemm_nt_kernel, dim3(SEQ / 64, SEQ / 64), dim3(256), 0, stream,
                       dec_e, attn_W, attn_b, attn_e, H, H, 0, 2 * H, SEQ);
    hipLaunchKernelGGL(gemm_nt_kernel, dim3(H / 64, SEQ / 64), dim3(256), 0, stream,
                       dec_e, comb_W, comb_b, comb_pre, H, H, 0, 2 * H, H);

    // phase 2: encoder recurrence
    {
        void* args[] = {(void*)&enc_Wh, (void*)&enc_bh, (void*)&enc_gi,
                        (void*)&enc_h_data, (void*)&enc_flag_h,
                        (void*)&dec_h_data, (void*)&dec_flag_h, (void*)&encH};
        hipLaunchCooperativeKernel((void*)enc_rnn_kernel, dim3(256), dim3(256),
                                   args, 0, stream);
    }

    // phase 2.5: M = comb_W[:,H:] @ encH^T
    hipLaunchKernelGGL(gemm_nt_kernel, dim3(SEQ / 64, H / 64), dim3(256), 0, stream,
                       comb_W, encH, (const float*)nullptr, Mmat, H, 2 * H, H, H, SEQ);

    // phase 3: decoder recurrence
    {
        void* args[] = {(void*)&attn_W, (void*)&attn_e, (void*)&Mmat, (void*)&comb_pre,
                        (void*)&dec_Wi, (void*)&dec_Wh, (void*)&dec_bi, (void*)&dec_bh,
                        (void*)&dec_h_data, (void*)&dec_flag_h,
                        (void*)&dec_c_data, (void*)&dec_flag_c,
                        (void*)&score_slots, (void*)&hs_dec};
        hipLaunchCooperativeKernel((void*)dec_rnn_kernel, dim3(256), dim3(256),
                                   args, 0, stream);
    }

    // phase 4: logits = hs_dec @ out_W^T + out_b
    hipLaunchKernelGGL(gemm_nt_kernel, dim3(VOUT / 64, SEQ / 64), dim3(256), 0, stream,
                       hs_dec, out_W, out_b, logits, H, H, 0, H, VOUT);

    // phase 5: NLL + total
    hipLaunchKernelGGL(nll_kernel, dim3(SEQ), dim3(256), 0, stream,
                       logits, target_ids, nll);
    hipLaunchKernelGGL(sum_kernel, dim3(1), dim3(256), 0, stream, nll, out);
}